// Round 9
// baseline (966.351 us; speedup 1.0000x reference)
//
#include <hip/hip_runtime.h>

// snntorch Synaptic scan, reset_mechanism='zero'.
// T=512, B=32, N=4096. x: (T,B,N) f32. out: [spk | syn | mem], each (T,B,N) f32.
// Per step: keep = (mem_prev <= thr); syn' = a*syn + x; mem' = b*mem + syn';
//           syn' *= keep; mem' *= keep; spk = (mem' > thr).
//
// R2 (resubmitted after 7th GPU-acquisition timeout; still unmeasured):
// store-hazard decoupling. Evidence: R0 (vec4, 2 waves/CU) == R1 (scalar,
// 8 waves/CU, depth-4 prefetch, nt) == ~443us kernel => wall is NOT occupancy/
// latency/width. 443us/512 steps = 2076 cy/step ~= one loaded store-completion
// latency: the loop-carried syn/mem VGPRs are stored then redefined next step,
// forcing a tight s_waitcnt vmcnt() on store retirement EVERY step.
// Fix: (a) store COPIES of syn/mem, never the recurrence registers;
//      (b) 16-step groups with all 48 store temps pinned live to group bottom
//          (empty asm) -> 48 distinct VGPRs, redefined a full group later;
//      (c) next-group x loads issued before the group's stores (load waits
//          become vmcnt(~48), never draining stores);
//      (d) plain stores (L2-acknowledged), not nontemporal.
// Numerics: __fmul_rn/__fadd_rn, identical op order as passing R0/R1 kernels.

#define T_STEPS 512
#define BN      131072          // 32*4096 elements per timestep

#define REPEAT16(M) M(0) M(1) M(2) M(3) M(4) M(5) M(6) M(7) \
                    M(8) M(9) M(10) M(11) M(12) M(13) M(14) M(15)

__global__ __launch_bounds__(256) void snn_synaptic_kernel(
    const float* __restrict__ x, float* __restrict__ out) {
  const int i = blockIdx.x * 256 + threadIdx.x;   // 0 .. BN-1

  float* __restrict__ spk_o = out;
  float* __restrict__ syn_o = out + (long long)T_STEPS * BN;
  float* __restrict__ mem_o = out + 2LL * T_STEPS * BN;

  float syn = 0.f, mem = 0.f;

  // preload x for steps 0..15
  #define DECLXP(s) float xp##s = x[(s) * BN + i];
  REPEAT16(DECLXP)
  #undef DECLXP

  for (int tb = 0; tb < T_STEPS; tb += 16) {
    // next-group base (wraps to 0 on the last group: valid, harmless re-read)
    const int nb = ((tb + 16) & (T_STEPS - 1)) * BN + i;

    // issue next-group loads FIRST: all of this group's stores are younger,
    // so the next iteration's load-wait is vmcnt(~48) and never drains stores.
    #define LOADN(s) const float xn##s = x[nb + (s) * BN];
    REPEAT16(LOADN)
    #undef LOADN

    const int ob = tb * BN + i;

    // 16 steps; stored values go through per-step temps (q_*), never syn/mem.
    #define STEP(s)                                                  \
      const float keep##s = (mem > 2.0f) ? 0.0f : 1.0f;              \
      syn = __fadd_rn(__fmul_rn(0.1f, syn), xp##s);                  \
      mem = __fadd_rn(__fmul_rn(0.96f, mem), syn);                   \
      syn *= keep##s;                                                \
      mem *= keep##s;                                                \
      const float q_spk##s = (mem > 2.0f) ? 1.0f : 0.0f;             \
      const float q_syn##s = syn;                                    \
      const float q_mem##s = mem;                                    \
      {                                                              \
        const int o = ob + (s) * BN;                                 \
        spk_o[o] = q_spk##s;                                         \
        syn_o[o] = q_syn##s;                                         \
        mem_o[o] = q_mem##s;                                         \
      }
    REPEAT16(STEP)
    #undef STEP

    // pin all 48 stored temps live to here: forces 48 distinct VGPRs (the
    // copies materialize), so each store's source register is redefined a
    // full 16-step group later -> store-retire waits tolerate ~48 in flight.
    asm volatile("" :: "v"(q_spk0),  "v"(q_spk1),  "v"(q_spk2),  "v"(q_spk3),
                       "v"(q_spk4),  "v"(q_spk5),  "v"(q_spk6),  "v"(q_spk7),
                       "v"(q_spk8),  "v"(q_spk9),  "v"(q_spk10), "v"(q_spk11),
                       "v"(q_spk12), "v"(q_spk13), "v"(q_spk14), "v"(q_spk15));
    asm volatile("" :: "v"(q_syn0),  "v"(q_syn1),  "v"(q_syn2),  "v"(q_syn3),
                       "v"(q_syn4),  "v"(q_syn5),  "v"(q_syn6),  "v"(q_syn7),
                       "v"(q_syn8),  "v"(q_syn9),  "v"(q_syn10), "v"(q_syn11),
                       "v"(q_syn12), "v"(q_syn13), "v"(q_syn14), "v"(q_syn15));
    asm volatile("" :: "v"(q_mem0),  "v"(q_mem1),  "v"(q_mem2),  "v"(q_mem3),
                       "v"(q_mem4),  "v"(q_mem5),  "v"(q_mem6),  "v"(q_mem7),
                       "v"(q_mem8),  "v"(q_mem9),  "v"(q_mem10), "v"(q_mem11),
                       "v"(q_mem12), "v"(q_mem13), "v"(q_mem14), "v"(q_mem15));

    // rotate prefetched x into place for the next group
    #define ROT(s) xp##s = xn##s;
    REPEAT16(ROT)
    #undef ROT
  }
}

extern "C" void kernel_launch(void* const* d_in, const int* in_sizes, int n_in,
                              void* d_out, int out_size, void* d_ws, size_t ws_size,
                              hipStream_t stream) {
  const float* x = (const float*)d_in[0];
  float* out = (float*)d_out;
  snn_synaptic_kernel<<<dim3(BN / 256), dim3(256), 0, stream>>>(x, out);
}